// Round 5
// baseline (7844.413 us; speedup 1.0000x reference)
//
#include <hip/hip_runtime.h>
#include <cstddef>

// ---------------------------------------------------------------------------
// RelGraphConv GNN, 10 layers. Round 5: dst-tile fused msg kernel.
// msg[d] = b + W_loop x_d + sum_r W_r (sum_{e: etype=r, dst=d} x_src)
// computed per 128-dst tile with LDS f32 gather-sum + MFMA, zero global
// atomics (round 4's edge_gemm streamed 300 MB/layer of atomic f32 adds).
// Edges bucketed once by (dstTile, relation): 6256 bins, ~96 edges each.
// N=100000, E=600000, F=64, H=128, R=8.
// ---------------------------------------------------------------------------

#define HID 128
#define NREL 8
#define NL 10

typedef __attribute__((ext_vector_type(8))) __bf16 bf16x8;
typedef __attribute__((ext_vector_type(4))) float f32x4;

// --- batched transpose + f32->bf16: W[z][K][Nc] -> Wt[z][Nc][K] ---
__global__ __launch_bounds__(256) void k_transpose(const float* __restrict__ W,
                                                   __bf16* __restrict__ Wt,
                                                   int K, int Nc) {
  __shared__ float t[32][33];
  const float* Wz = W + (size_t)blockIdx.z * K * Nc;
  __bf16* Wtz = Wt + (size_t)blockIdx.z * K * Nc;
  int n0 = blockIdx.x * 32, k0 = blockIdx.y * 32;
#pragma unroll
  for (int i = 0; i < 4; i++) {
    int k = k0 + threadIdx.y + i * 8;
    int n = n0 + threadIdx.x;
    t[threadIdx.y + i * 8][threadIdx.x] = Wz[(size_t)k * Nc + n];
  }
  __syncthreads();
#pragma unroll
  for (int i = 0; i < 4; i++) {
    int n = n0 + threadIdx.y + i * 8;
    int k = k0 + threadIdx.x;
    Wtz[(size_t)n * K + k] = (__bf16)t[threadIdx.x][threadIdx.y + i * 8];
  }
}

// --- f32 -> bf16 elementwise (n4 = count/4) ---
__global__ __launch_bounds__(256) void k_cvt(const float* __restrict__ x,
                                             __bf16* __restrict__ y, int n4) {
  int i = blockIdx.x * 256 + threadIdx.x;
  if (i < n4) {
    float4 f = ((const float4*)x)[i];
    __bf16 o[4] = {(__bf16)f.x, (__bf16)f.y, (__bf16)f.z, (__bf16)f.w};
    *(uint2*)(y + (size_t)i * 4) = *(uint2*)o;
  }
}

// ====================== (dstTile, relation) bucketing =======================
__global__ __launch_bounds__(256) void k_zero(int* __restrict__ p, int n) {
  for (int i = blockIdx.x * 256 + threadIdx.x; i < n; i += gridDim.x * 256) p[i] = 0;
}

__global__ __launch_bounds__(256) void k_hist_bin(const int* __restrict__ et,
                                                  const int* __restrict__ dst,
                                                  int E, int* __restrict__ binCnt) {
  int e = blockIdx.x * 256 + threadIdx.x;
  if (e < E) atomicAdd(&binCnt[(dst[e] >> 7) * NREL + et[e]], 1);
}

// single-block prefix sum over nb bins -> binStart[nb+1], binCur[nb]
__global__ __launch_bounds__(256) void k_scan_bin(const int* __restrict__ binCnt,
                                                  int nb, int* __restrict__ binStart,
                                                  int* __restrict__ binCur) {
  __shared__ int part[257];
  int chunk = (nb + 255) / 256;
  int lo = threadIdx.x * chunk, hi = min(nb, lo + chunk);
  int s = 0;
  for (int i = lo; i < hi; i++) s += binCnt[i];
  part[threadIdx.x] = s;
  __syncthreads();
  if (threadIdx.x == 0) {
    int a = 0;
    for (int i = 0; i < 256; i++) { int v = part[i]; part[i] = a; a += v; }
    part[256] = a;
    binStart[nb] = a;
  }
  __syncthreads();
  int run = part[threadIdx.x];
  for (int i = lo; i < hi; i++) {
    binStart[i] = run;
    binCur[i] = run;
    run += binCnt[i];
  }
}

// pack edge: src (17b) | local-dst (7b) << 17
__global__ __launch_bounds__(256) void k_place_bin(const int* __restrict__ et,
                                                   const int* __restrict__ src,
                                                   const int* __restrict__ dst,
                                                   int* __restrict__ binCur,
                                                   int* __restrict__ epk, int E) {
  int e = blockIdx.x * 256 + threadIdx.x;
  if (e < E) {
    int d = dst[e];
    int bin = (d >> 7) * NREL + et[e];
    int p = atomicAdd(&binCur[bin], 1);
    epk[p] = src[e] | ((d & 127) << 17);
  }
}

// ========================= fused dst-tile msg kernel ========================
// One block per 128-dst tile. acc = b + W_loop x + sum_r W_r S_r, S_r gathered
// in LDS f32 (LDS atomics), MFMA per relation. msg written once, no atomics.
__global__ __launch_bounds__(256) void node_msg(
    const __bf16* __restrict__ x,
    const __bf16* __restrict__ wt_rel_l,   // [8][128][128] (n-major)
    const __bf16* __restrict__ wt_loop_l,  // [128][128]
    const float* __restrict__ b_rel_l,     // [128]
    const int* __restrict__ binStart,
    const int* __restrict__ epk,
    float* __restrict__ msg, int N) {
  __shared__ float S[128][132];     // gather-sum tile, f32 (pad: 2-way banks)
  __shared__ __bf16 Ws[128][136];   // staged weight [n][k]

  const int tid = threadIdx.x;
  const int g = blockIdx.x;
  const int d0 = g * 128;
  const int lane = tid & 63, w = tid >> 6;
  const int ml = lane & 15, q = lane >> 4;
  const int wr = (w >> 1) * 64, wc = (w & 1) * 64;

  f32x4 acc[4][4];
#pragma unroll
  for (int i = 0; i < 4; i++)
#pragma unroll
    for (int j = 0; j < 4; j++)
#pragma unroll
      for (int z = 0; z < 4; z++) acc[i][j][z] = 0.f;

  // ---- self-loop: Ws = W_loop, A-frags direct from global x tile ----
#pragma unroll
  for (int i = 0; i < 8; i++) {
    int ci = tid + i * 256;
    int row = ci >> 4, kc = ci & 15;
    *(bf16x8*)(&Ws[row][kc * 8]) =
        *(const bf16x8*)(wt_loop_l + (size_t)row * HID + kc * 8);
  }
  __syncthreads();
#pragma unroll
  for (int kk = 0; kk < 4; kk++) {
    bf16x8 af[4], bfr[4];
#pragma unroll
    for (int i = 0; i < 4; i++) {
      int rr = d0 + wr + i * 16 + ml;
      rr = min(rr, N - 1);  // clamp; out-of-range rows are discarded at write
      af[i] = *(const bf16x8*)(x + (size_t)rr * HID + kk * 32 + q * 8);
    }
#pragma unroll
    for (int j = 0; j < 4; j++)
      bfr[j] = *(const bf16x8*)(&Ws[wc + j * 16 + ml][kk * 32 + q * 8]);
#pragma unroll
    for (int i = 0; i < 4; i++)
#pragma unroll
      for (int j = 0; j < 4; j++)
        acc[i][j] = __builtin_amdgcn_mfma_f32_16x16x32_bf16(af[i], bfr[j],
                                                            acc[i][j], 0, 0, 0);
  }

  // ---- relations ----
  for (int r = 0; r < NREL; r++) {
    __syncthreads();  // protect S/Ws reuse
    // zero S (128*132 f32 = 4224 f32x4)
    for (int i = tid; i < 128 * 132 / 4; i += 256) ((f32x4*)S)[i] = (f32x4)0.f;
    // stage Ws = W_rel[l][r]
    const __bf16* W = wt_rel_l + (size_t)r * HID * HID;
#pragma unroll
    for (int i = 0; i < 8; i++) {
      int ci = tid + i * 256;
      int row = ci >> 4, kc = ci & 15;
      *(bf16x8*)(&Ws[row][kc * 8]) = *(const bf16x8*)(W + (size_t)row * HID + kc * 8);
    }
    __syncthreads();

    // gather-sum edges of bin (g, r): wave-strided, 64 lanes = 128 features
    int b = g * NREL + r;
    int lo = binStart[b], hi = binStart[b + 1];
    for (int i = lo + w; i < hi; i += 4) {
      int p = epk[i];  // wave-uniform broadcast load
      int s = p & 0x1FFFF, ld = p >> 17;
      unsigned int v = *(const unsigned int*)(x + (size_t)s * HID + lane * 2);
      union { unsigned int u; float f; } c0, c1;
      c0.u = v << 16;
      c1.u = v & 0xFFFF0000u;
      atomicAdd(&S[ld][lane * 2], c0.f);
      atomicAdd(&S[ld][lane * 2 + 1], c1.f);
    }
    __syncthreads();

    // MFMA: A from S (f32 -> bf16), B from Ws
#pragma unroll
    for (int kk = 0; kk < 4; kk++) {
      bf16x8 af[4], bfr[4];
#pragma unroll
      for (int i = 0; i < 4; i++) {
        const float* sp = &S[wr + i * 16 + ml][kk * 32 + q * 8];
        f32x4 a0 = *(const f32x4*)sp;
        f32x4 a1 = *(const f32x4*)(sp + 4);
        bf16x8 t;
        t[0] = (__bf16)a0[0]; t[1] = (__bf16)a0[1];
        t[2] = (__bf16)a0[2]; t[3] = (__bf16)a0[3];
        t[4] = (__bf16)a1[0]; t[5] = (__bf16)a1[1];
        t[6] = (__bf16)a1[2]; t[7] = (__bf16)a1[3];
        af[i] = t;
      }
#pragma unroll
      for (int j = 0; j < 4; j++)
        bfr[j] = *(const bf16x8*)(&Ws[wc + j * 16 + ml][kk * 32 + q * 8]);
#pragma unroll
      for (int i = 0; i < 4; i++)
#pragma unroll
        for (int j = 0; j < 4; j++)
          acc[i][j] = __builtin_amdgcn_mfma_f32_16x16x32_bf16(af[i], bfr[j],
                                                              acc[i][j], 0, 0, 0);
    }
  }

  // ---- epilogue: + bias, single non-atomic write ----
#pragma unroll
  for (int i = 0; i < 4; i++) {
#pragma unroll
    for (int z = 0; z < 4; z++) {
      int grow = d0 + wr + i * 16 + q * 4 + z;
      if (grow >= N) continue;
#pragma unroll
      for (int j = 0; j < 4; j++) {
        int col = wc + j * 16 + ml;
        msg[(size_t)grow * HID + col] = acc[i][j][z] + b_rel_l[col];
      }
    }
  }
}

// ---------------------------------------------------------------------------
// bf16 MFMA GEMM (dense): C = act(concat(A0,A1) @ B + bias)   [proven]
// ---------------------------------------------------------------------------
__global__ __launch_bounds__(256) void gemm_bf16(
    const __bf16* __restrict__ A0, const void* __restrict__ A1v, int a1_f32,
    int K0, int K,
    const __bf16* __restrict__ Bt, const float* __restrict__ bias,
    __bf16* __restrict__ Cb, float* __restrict__ Cf,
    int M, int Nc, int act) {
  __shared__ __bf16 As[128][72];
  __shared__ __bf16 Bs[128][72];
  const int tid = threadIdx.x;
  const int m0 = blockIdx.x * 128;
  const int bn0 = blockIdx.y * 128;
  const int lane = tid & 63;
  const int w = tid >> 6;
  const int ml = lane & 15, q = lane >> 4;
  const int wr = (w >> 1) * 64, wc = (w & 1) * 64;
  const int KA1 = K - K0;

  f32x4 acc[4][4];
#pragma unroll
  for (int i = 0; i < 4; i++)
#pragma unroll
    for (int j = 0; j < 4; j++)
#pragma unroll
      for (int r = 0; r < 4; r++) acc[i][j][r] = 0.f;

  for (int k0 = 0; k0 < K; k0 += 64) {
#pragma unroll
    for (int i = 0; i < 4; i++) {
      int ci = tid + i * 256;
      int row = ci >> 3;
      int kc = ci & 7;
      int gk = k0 + kc * 8;
      int gr = m0 + row;
      bf16x8 va;
#pragma unroll
      for (int z = 0; z < 8; z++) va[z] = (__bf16)0.f;
      if (gr < M) {
        if (gk < K0) {
          va = *(const bf16x8*)(A0 + (size_t)gr * K0 + gk);
        } else if (!a1_f32) {
          va = *(const bf16x8*)((const __bf16*)A1v + (size_t)gr * KA1 + (gk - K0));
        } else {
          const float* p = (const float*)A1v + (size_t)gr * KA1 + (gk - K0);
          float4 f0 = *(const float4*)p;
          float4 f1 = *(const float4*)(p + 4);
          va[0] = (__bf16)f0.x; va[1] = (__bf16)f0.y;
          va[2] = (__bf16)f0.z; va[3] = (__bf16)f0.w;
          va[4] = (__bf16)f1.x; va[5] = (__bf16)f1.y;
          va[6] = (__bf16)f1.z; va[7] = (__bf16)f1.w;
        }
      }
      *(bf16x8*)(&As[row][kc * 8]) = va;
      bf16x8 vb = *(const bf16x8*)(Bt + (size_t)(bn0 + row) * K + gk);
      *(bf16x8*)(&Bs[row][kc * 8]) = vb;
    }
    __syncthreads();
#pragma unroll
    for (int kk = 0; kk < 2; kk++) {
      bf16x8 af[4], bfr[4];
#pragma unroll
      for (int i = 0; i < 4; i++)
        af[i] = *(const bf16x8*)(&As[wr + i * 16 + ml][kk * 32 + q * 8]);
#pragma unroll
      for (int j = 0; j < 4; j++)
        bfr[j] = *(const bf16x8*)(&Bs[wc + j * 16 + ml][kk * 32 + q * 8]);
#pragma unroll
      for (int i = 0; i < 4; i++)
#pragma unroll
        for (int j = 0; j < 4; j++)
          acc[i][j] = __builtin_amdgcn_mfma_f32_16x16x32_bf16(af[i], bfr[j],
                                                              acc[i][j], 0, 0, 0);
    }
    __syncthreads();
  }

#pragma unroll
  for (int i = 0; i < 4; i++) {
#pragma unroll
    for (int r = 0; r < 4; r++) {
      int grow = m0 + wr + i * 16 + q * 4 + r;
      if (grow >= M) continue;
#pragma unroll
      for (int j = 0; j < 4; j++) {
        int col = bn0 + wc + j * 16 + ml;
        float v = acc[i][j][r];
        if (bias) v += bias[col];
        if (act) v = tanhf(v);
        if (Cb) Cb[(size_t)grow * Nc + col] = (__bf16)v;
        if (Cf) Cf[(size_t)grow * Nc + col] = v;
      }
    }
  }
}

extern "C" void kernel_launch(void* const* d_in, const int* in_sizes, int n_in,
                              void* d_out, int out_size, void* d_ws, size_t ws_size,
                              hipStream_t stream) {
  const float* feats  = (const float*)d_in[0];
  const int*   src    = (const int*)d_in[1];
  const int*   dst    = (const int*)d_in[2];
  const int*   etype  = (const int*)d_in[3];
  const float* W_in   = (const float*)d_in[4];
  const float* b_in   = (const float*)d_in[5];
  const float* W_rel  = (const float*)d_in[6];
  const float* W_loop = (const float*)d_in[7];
  const float* b_rel  = (const float*)d_in[8];
  const float* W_u1   = (const float*)d_in[9];
  const float* b_u1   = (const float*)d_in[10];
  const float* W_u2   = (const float*)d_in[11];
  const float* b_u2   = (const float*)d_in[12];

  const int E = in_sizes[1];
  const int N = in_sizes[0] / 64;
  const int NT = (N + 127) / 128;      // dst tiles
  const int NBIN = NT * NREL;          // (tile, relation) bins

  // --- workspace layout ---
  __bf16* xb0 = (__bf16*)d_ws;                        // N*128
  __bf16* xb1 = xb0 + (size_t)N * HID;                // N*128
  float*  msg = (float*)(xb1 + (size_t)N * HID);      // N*128 f32
  __bf16* mid = (__bf16*)(msg + (size_t)N * HID);     // N*256 bf16
  __bf16* featsb = mid + (size_t)N * 256;             // N*64
  __bf16* wt_in   = featsb + (size_t)N * 64;          // [128][64]
  __bf16* wt_rel  = wt_in + 128 * 64;                 // [80][128][128]
  __bf16* wt_loop = wt_rel + (size_t)80 * 128 * 128;  // [10][128][128]
  __bf16* wt_u1   = wt_loop + (size_t)10 * 128 * 128; // [10][256][256]
  __bf16* wt_u2   = wt_u1 + (size_t)10 * 256 * 256;   // [10][128][384]
  int* binCnt   = (int*)(wt_u2 + (size_t)10 * 128 * 384); // NBIN
  int* binStart = binCnt + NBIN;                      // NBIN+1
  int* binCur   = binStart + NBIN + 1;                // NBIN
  int* epk      = binCur + NBIN;                      // E

  // --- weight transpose+convert + feats convert ---
  k_transpose<<<dim3(4, 2, 1),   dim3(32, 8), 0, stream>>>(W_in,   wt_in,   64, 128);
  k_transpose<<<dim3(4, 4, 80),  dim3(32, 8), 0, stream>>>(W_rel,  wt_rel,  128, 128);
  k_transpose<<<dim3(4, 4, 10),  dim3(32, 8), 0, stream>>>(W_loop, wt_loop, 128, 128);
  k_transpose<<<dim3(8, 8, 10),  dim3(32, 8), 0, stream>>>(W_u1,   wt_u1,   256, 256);
  k_transpose<<<dim3(4, 12, 10), dim3(32, 8), 0, stream>>>(W_u2,   wt_u2,   384, 128);
  k_cvt<<<(N * 64 / 4 + 255) / 256, 256, 0, stream>>>(feats, featsb, N * 64 / 4);

  // --- (dstTile, relation) bucketing, once per launch ---
  k_zero<<<64, 256, 0, stream>>>(binCnt, NBIN);
  k_hist_bin<<<(E + 255) / 256, 256, 0, stream>>>(etype, dst, E, binCnt);
  k_scan_bin<<<1, 256, 0, stream>>>(binCnt, NBIN, binStart, binCur);
  k_place_bin<<<(E + 255) / 256, 256, 0, stream>>>(etype, src, dst, binCur, epk, E);

  const dim3 blk(256);
  const int gm = (N + 127) / 128;
  const dim3 g1(gm, 1), g2(gm, 2);

  // input projection
  gemm_bf16<<<g1, blk, 0, stream>>>(featsb, nullptr, 0, 64, 64, wt_in, b_in,
                                    xb0, nullptr, N, HID, 1);

  for (int l = 0; l < NL; l++) {
    const __bf16* xin = (l & 1) ? xb1 : xb0;
    __bf16* xout = (l & 1) ? xb0 : xb1;

    // fused: msg = b_rel + W_loop x + sum_r W_r (gather-sum x[src])
    node_msg<<<NT, blk, 0, stream>>>(xin,
                                     wt_rel + (size_t)l * NREL * HID * HID,
                                     wt_loop + (size_t)l * HID * HID,
                                     b_rel + (size_t)l * HID,
                                     binStart, epk, msg, N);

    // mid = tanh([x | msg] @ W_u1[l] + b_u1[l])
    gemm_bf16<<<g2, blk, 0, stream>>>(xin, msg, 1, HID, 256,
                                      wt_u1 + (size_t)l * 256 * 256,
                                      b_u1 + (size_t)l * 256,
                                      mid, nullptr, N, 256, 1);

    // x' = tanh([x | mid] @ W_u2[l] + b_u2[l]); last layer -> f32 d_out
    gemm_bf16<<<g1, blk, 0, stream>>>(xin, mid, 0, HID, 384,
                                      wt_u2 + (size_t)l * HID * 384,
                                      b_u2 + (size_t)l * HID,
                                      (l == NL - 1) ? nullptr : xout,
                                      (l == NL - 1) ? (float*)d_out : nullptr,
                                      N, HID, 1);
  }
}

// Round 6
// 7554.253 us; speedup vs baseline: 1.0384x; 1.0384x over previous
//
#include <hip/hip_runtime.h>
#include <cstddef>

// ---------------------------------------------------------------------------
// RelGraphConv GNN, 10 layers. Round 6: node_msg de-latency-ified.
//   - Ws LDS staging dropped (B-frags direct from L2-hot global) -> 67.6 KB
//     LDS -> 2 blocks/CU (was 1, Occupancy 9.3%)
//   - gather loop: per-wave contiguous chunks, manual 4-deep ILP
//   - msg stored bf16 (numerically identical: u1 rounded it to bf16 anyway)
// N=100000, E=600000, F=64, H=128, R=8.
// ---------------------------------------------------------------------------

#define HID 128
#define NREL 8
#define NL 10

typedef __attribute__((ext_vector_type(8))) __bf16 bf16x8;
typedef __attribute__((ext_vector_type(4))) float f32x4;

// --- batched transpose + f32->bf16: W[z][K][Nc] -> Wt[z][Nc][K] ---
__global__ __launch_bounds__(256) void k_transpose(const float* __restrict__ W,
                                                   __bf16* __restrict__ Wt,
                                                   int K, int Nc) {
  __shared__ float t[32][33];
  const float* Wz = W + (size_t)blockIdx.z * K * Nc;
  __bf16* Wtz = Wt + (size_t)blockIdx.z * K * Nc;
  int n0 = blockIdx.x * 32, k0 = blockIdx.y * 32;
#pragma unroll
  for (int i = 0; i < 4; i++) {
    int k = k0 + threadIdx.y + i * 8;
    int n = n0 + threadIdx.x;
    t[threadIdx.y + i * 8][threadIdx.x] = Wz[(size_t)k * Nc + n];
  }
  __syncthreads();
#pragma unroll
  for (int i = 0; i < 4; i++) {
    int n = n0 + threadIdx.y + i * 8;
    int k = k0 + threadIdx.x;
    Wtz[(size_t)n * K + k] = (__bf16)t[threadIdx.x][threadIdx.y + i * 8];
  }
}

// --- f32 -> bf16 elementwise (n4 = count/4) ---
__global__ __launch_bounds__(256) void k_cvt(const float* __restrict__ x,
                                             __bf16* __restrict__ y, int n4) {
  int i = blockIdx.x * 256 + threadIdx.x;
  if (i < n4) {
    float4 f = ((const float4*)x)[i];
    __bf16 o[4] = {(__bf16)f.x, (__bf16)f.y, (__bf16)f.z, (__bf16)f.w};
    *(uint2*)(y + (size_t)i * 4) = *(uint2*)o;
  }
}

// ====================== (dstTile, relation) bucketing =======================
__global__ __launch_bounds__(256) void k_zero(int* __restrict__ p, int n) {
  for (int i = blockIdx.x * 256 + threadIdx.x; i < n; i += gridDim.x * 256) p[i] = 0;
}

__global__ __launch_bounds__(256) void k_hist_bin(const int* __restrict__ et,
                                                  const int* __restrict__ dst,
                                                  int E, int* __restrict__ binCnt) {
  int e = blockIdx.x * 256 + threadIdx.x;
  if (e < E) atomicAdd(&binCnt[(dst[e] >> 7) * NREL + et[e]], 1);
}

__global__ __launch_bounds__(256) void k_scan_bin(const int* __restrict__ binCnt,
                                                  int nb, int* __restrict__ binStart,
                                                  int* __restrict__ binCur) {
  __shared__ int part[257];
  int chunk = (nb + 255) / 256;
  int lo = threadIdx.x * chunk, hi = min(nb, lo + chunk);
  int s = 0;
  for (int i = lo; i < hi; i++) s += binCnt[i];
  part[threadIdx.x] = s;
  __syncthreads();
  if (threadIdx.x == 0) {
    int a = 0;
    for (int i = 0; i < 256; i++) { int v = part[i]; part[i] = a; a += v; }
    part[256] = a;
    binStart[nb] = a;
  }
  __syncthreads();
  int run = part[threadIdx.x];
  for (int i = lo; i < hi; i++) {
    binStart[i] = run;
    binCur[i] = run;
    run += binCnt[i];
  }
}

// pack edge: src (17b) | local-dst (7b) << 17
__global__ __launch_bounds__(256) void k_place_bin(const int* __restrict__ et,
                                                   const int* __restrict__ src,
                                                   const int* __restrict__ dst,
                                                   int* __restrict__ binCur,
                                                   int* __restrict__ epk, int E) {
  int e = blockIdx.x * 256 + threadIdx.x;
  if (e < E) {
    int d = dst[e];
    int bin = (d >> 7) * NREL + et[e];
    int p = atomicAdd(&binCur[bin], 1);
    epk[p] = src[e] | ((d & 127) << 17);
  }
}

// ========================= fused dst-tile msg kernel ========================
__device__ __forceinline__ void s_addpair(float (*S)[132], int ld, int lane,
                                          unsigned v) {
  union { unsigned u; float f; } c0, c1;
  c0.u = v << 16;
  c1.u = v & 0xFFFF0000u;
  atomicAdd(&S[ld][lane * 2], c0.f);
  atomicAdd(&S[ld][lane * 2 + 1], c1.f);
}

// One block per 128-dst tile. acc = b + W_loop x + sum_r W_r S_r; S_r gathered
// into LDS f32 (4-deep ILP), B-frags direct from global. msg written once (bf16).
__global__ __launch_bounds__(256) void node_msg(
    const __bf16* __restrict__ x,
    const __bf16* __restrict__ wt_rel_l,   // [8][128][128] (n-major)
    const __bf16* __restrict__ wt_loop_l,  // [128][128]
    const float* __restrict__ b_rel_l,     // [128]
    const int* __restrict__ binStart,
    const int* __restrict__ epk,
    __bf16* __restrict__ msgb, int N) {
  __shared__ float S[128][132];  // gather-sum tile, f32

  const int tid = threadIdx.x;
  const int g = blockIdx.x;
  const int d0 = g * 128;
  const int lane = tid & 63, w = tid >> 6;
  const int ml = lane & 15, q = lane >> 4;
  const int wr = (w >> 1) * 64, wc = (w & 1) * 64;

  f32x4 acc[4][4];
#pragma unroll
  for (int i = 0; i < 4; i++)
#pragma unroll
    for (int j = 0; j < 4; j++)
#pragma unroll
      for (int z = 0; z < 4; z++) acc[i][j][z] = 0.f;

  // ---- self-loop: A direct from global x, B direct from wt_loop ----
#pragma unroll
  for (int kk = 0; kk < 4; kk++) {
    bf16x8 af[4], bfr[4];
#pragma unroll
    for (int i = 0; i < 4; i++) {
      int rr = min(d0 + wr + i * 16 + ml, N - 1);  // clamp; tail discarded at write
      af[i] = *(const bf16x8*)(x + (size_t)rr * HID + kk * 32 + q * 8);
    }
#pragma unroll
    for (int j = 0; j < 4; j++)
      bfr[j] = *(const bf16x8*)(wt_loop_l + (size_t)(wc + j * 16 + ml) * HID +
                                kk * 32 + q * 8);
#pragma unroll
    for (int i = 0; i < 4; i++)
#pragma unroll
      for (int j = 0; j < 4; j++)
        acc[i][j] = __builtin_amdgcn_mfma_f32_16x16x32_bf16(af[i], bfr[j],
                                                            acc[i][j], 0, 0, 0);
  }

  // ---- relations ----
  for (int r = 0; r < NREL; r++) {
    __syncthreads();  // S free (previous MFMA reads done)
    for (int i = tid; i < 128 * 132 / 4; i += 256) ((f32x4*)S)[i] = (f32x4)0.f;
    __syncthreads();  // S zeroed before atomics

    // gather: per-wave contiguous chunk, 4-deep ILP
    int bidx = g * NREL + r;
    int lo = binStart[bidx], hi = binStart[bidx + 1];
    int chunk = (hi - lo + 3) >> 2;
    int i = lo + w * chunk;
    int iend = min(hi, i + chunk);
    for (; i + 3 < iend; i += 4) {
      int p0 = epk[i], p1 = epk[i + 1], p2 = epk[i + 2], p3 = epk[i + 3];
      unsigned v0 = *(const unsigned*)(x + (size_t)(p0 & 0x1FFFF) * HID + lane * 2);
      unsigned v1 = *(const unsigned*)(x + (size_t)(p1 & 0x1FFFF) * HID + lane * 2);
      unsigned v2 = *(const unsigned*)(x + (size_t)(p2 & 0x1FFFF) * HID + lane * 2);
      unsigned v3 = *(const unsigned*)(x + (size_t)(p3 & 0x1FFFF) * HID + lane * 2);
      s_addpair(S, p0 >> 17, lane, v0);
      s_addpair(S, p1 >> 17, lane, v1);
      s_addpair(S, p2 >> 17, lane, v2);
      s_addpair(S, p3 >> 17, lane, v3);
    }
    for (; i < iend; i++) {
      int p = epk[i];
      unsigned v = *(const unsigned*)(x + (size_t)(p & 0x1FFFF) * HID + lane * 2);
      s_addpair(S, p >> 17, lane, v);
    }
    __syncthreads();  // gather complete

    // MFMA: A from S (f32 -> bf16), B direct from global
    const __bf16* W = wt_rel_l + (size_t)r * HID * HID;
#pragma unroll
    for (int kk = 0; kk < 4; kk++) {
      bf16x8 af[4], bfr[4];
#pragma unroll
      for (int i = 0; i < 4; i++) {
        const float* sp = &S[wr + i * 16 + ml][kk * 32 + q * 8];
        f32x4 a0 = *(const f32x4*)sp;
        f32x4 a1 = *(const f32x4*)(sp + 4);
        bf16x8 t;
        t[0] = (__bf16)a0[0]; t[1] = (__bf16)a0[1];
        t[2] = (__bf16)a0[2]; t[3] = (__bf16)a0[3];
        t[4] = (__bf16)a1[0]; t[5] = (__bf16)a1[1];
        t[6] = (__bf16)a1[2]; t[7] = (__bf16)a1[3];
        af[i] = t;
      }
#pragma unroll
      for (int j = 0; j < 4; j++)
        bfr[j] = *(const bf16x8*)(W + (size_t)(wc + j * 16 + ml) * HID +
                                  kk * 32 + q * 8);
#pragma unroll
      for (int i = 0; i < 4; i++)
#pragma unroll
        for (int j = 0; j < 4; j++)
          acc[i][j] = __builtin_amdgcn_mfma_f32_16x16x32_bf16(af[i], bfr[j],
                                                              acc[i][j], 0, 0, 0);
    }
  }

  // ---- epilogue: + bias, single non-atomic bf16 write ----
#pragma unroll
  for (int i = 0; i < 4; i++) {
#pragma unroll
    for (int z = 0; z < 4; z++) {
      int grow = d0 + wr + i * 16 + q * 4 + z;
      if (grow >= N) continue;
#pragma unroll
      for (int j = 0; j < 4; j++) {
        int col = wc + j * 16 + ml;
        msgb[(size_t)grow * HID + col] = (__bf16)(acc[i][j][z] + b_rel_l[col]);
      }
    }
  }
}

// ---------------------------------------------------------------------------
// bf16 MFMA GEMM (dense): C = act(concat(A0,A1) @ B + bias)   [proven]
// ---------------------------------------------------------------------------
__global__ __launch_bounds__(256) void gemm_bf16(
    const __bf16* __restrict__ A0, const void* __restrict__ A1v, int a1_f32,
    int K0, int K,
    const __bf16* __restrict__ Bt, const float* __restrict__ bias,
    __bf16* __restrict__ Cb, float* __restrict__ Cf,
    int M, int Nc, int act) {
  __shared__ __bf16 As[128][72];
  __shared__ __bf16 Bs[128][72];
  const int tid = threadIdx.x;
  const int m0 = blockIdx.x * 128;
  const int bn0 = blockIdx.y * 128;
  const int lane = tid & 63;
  const int w = tid >> 6;
  const int ml = lane & 15, q = lane >> 4;
  const int wr = (w >> 1) * 64, wc = (w & 1) * 64;
  const int KA1 = K - K0;

  f32x4 acc[4][4];
#pragma unroll
  for (int i = 0; i < 4; i++)
#pragma unroll
    for (int j = 0; j < 4; j++)
#pragma unroll
      for (int r = 0; r < 4; r++) acc[i][j][r] = 0.f;

  for (int k0 = 0; k0 < K; k0 += 64) {
#pragma unroll
    for (int i = 0; i < 4; i++) {
      int ci = tid + i * 256;
      int row = ci >> 3;
      int kc = ci & 7;
      int gk = k0 + kc * 8;
      int gr = m0 + row;
      bf16x8 va;
#pragma unroll
      for (int z = 0; z < 8; z++) va[z] = (__bf16)0.f;
      if (gr < M) {
        if (gk < K0) {
          va = *(const bf16x8*)(A0 + (size_t)gr * K0 + gk);
        } else if (!a1_f32) {
          va = *(const bf16x8*)((const __bf16*)A1v + (size_t)gr * KA1 + (gk - K0));
        } else {
          const float* p = (const float*)A1v + (size_t)gr * KA1 + (gk - K0);
          float4 f0 = *(const float4*)p;
          float4 f1 = *(const float4*)(p + 4);
          va[0] = (__bf16)f0.x; va[1] = (__bf16)f0.y;
          va[2] = (__bf16)f0.z; va[3] = (__bf16)f0.w;
          va[4] = (__bf16)f1.x; va[5] = (__bf16)f1.y;
          va[6] = (__bf16)f1.z; va[7] = (__bf16)f1.w;
        }
      }
      *(bf16x8*)(&As[row][kc * 8]) = va;
      bf16x8 vb = *(const bf16x8*)(Bt + (size_t)(bn0 + row) * K + gk);
      *(bf16x8*)(&Bs[row][kc * 8]) = vb;
    }
    __syncthreads();
#pragma unroll
    for (int kk = 0; kk < 2; kk++) {
      bf16x8 af[4], bfr[4];
#pragma unroll
      for (int i = 0; i < 4; i++)
        af[i] = *(const bf16x8*)(&As[wr + i * 16 + ml][kk * 32 + q * 8]);
#pragma unroll
      for (int j = 0; j < 4; j++)
        bfr[j] = *(const bf16x8*)(&Bs[wc + j * 16 + ml][kk * 32 + q * 8]);
#pragma unroll
      for (int i = 0; i < 4; i++)
#pragma unroll
        for (int j = 0; j < 4; j++)
          acc[i][j] = __builtin_amdgcn_mfma_f32_16x16x32_bf16(af[i], bfr[j],
                                                              acc[i][j], 0, 0, 0);
    }
    __syncthreads();
  }

#pragma unroll
  for (int i = 0; i < 4; i++) {
#pragma unroll
    for (int r = 0; r < 4; r++) {
      int grow = m0 + wr + i * 16 + q * 4 + r;
      if (grow >= M) continue;
#pragma unroll
      for (int j = 0; j < 4; j++) {
        int col = bn0 + wc + j * 16 + ml;
        float v = acc[i][j][r];
        if (bias) v += bias[col];
        if (act) v = tanhf(v);
        if (Cb) Cb[(size_t)grow * Nc + col] = (__bf16)v;
        if (Cf) Cf[(size_t)grow * Nc + col] = v;
      }
    }
  }
}

extern "C" void kernel_launch(void* const* d_in, const int* in_sizes, int n_in,
                              void* d_out, int out_size, void* d_ws, size_t ws_size,
                              hipStream_t stream) {
  const float* feats  = (const float*)d_in[0];
  const int*   src    = (const int*)d_in[1];
  const int*   dst    = (const int*)d_in[2];
  const int*   etype  = (const int*)d_in[3];
  const float* W_in   = (const float*)d_in[4];
  const float* b_in   = (const float*)d_in[5];
  const float* W_rel  = (const float*)d_in[6];
  const float* W_loop = (const float*)d_in[7];
  const float* b_rel  = (const float*)d_in[8];
  const float* W_u1   = (const float*)d_in[9];
  const float* b_u1   = (const float*)d_in[10];
  const float* W_u2   = (const float*)d_in[11];
  const float* b_u2   = (const float*)d_in[12];

  const int E = in_sizes[1];
  const int N = in_sizes[0] / 64;
  const int NT = (N + 127) / 128;      // dst tiles
  const int NBIN = NT * NREL;          // (tile, relation) bins

  // --- workspace layout ---
  __bf16* xb0 = (__bf16*)d_ws;                        // N*128
  __bf16* xb1 = xb0 + (size_t)N * HID;                // N*128
  __bf16* msgb = xb1 + (size_t)N * HID;               // N*128 bf16
  __bf16* mid = msgb + (size_t)N * HID;               // N*256 bf16
  __bf16* featsb = mid + (size_t)N * 256;             // N*64
  __bf16* wt_in   = featsb + (size_t)N * 64;          // [128][64]
  __bf16* wt_rel  = wt_in + 128 * 64;                 // [80][128][128]
  __bf16* wt_loop = wt_rel + (size_t)80 * 128 * 128;  // [10][128][128]
  __bf16* wt_u1   = wt_loop + (size_t)10 * 128 * 128; // [10][256][256]
  __bf16* wt_u2   = wt_u1 + (size_t)10 * 256 * 256;   // [10][128][384]
  int* binCnt   = (int*)(wt_u2 + (size_t)10 * 128 * 384); // NBIN
  int* binStart = binCnt + NBIN;                      // NBIN+1
  int* binCur   = binStart + NBIN + 1;                // NBIN
  int* epk      = binCur + NBIN;                      // E

  // --- weight transpose+convert + feats convert ---
  k_transpose<<<dim3(4, 2, 1),   dim3(32, 8), 0, stream>>>(W_in,   wt_in,   64, 128);
  k_transpose<<<dim3(4, 4, 80),  dim3(32, 8), 0, stream>>>(W_rel,  wt_rel,  128, 128);
  k_transpose<<<dim3(4, 4, 10),  dim3(32, 8), 0, stream>>>(W_loop, wt_loop, 128, 128);
  k_transpose<<<dim3(8, 8, 10),  dim3(32, 8), 0, stream>>>(W_u1,   wt_u1,   256, 256);
  k_transpose<<<dim3(4, 12, 10), dim3(32, 8), 0, stream>>>(W_u2,   wt_u2,   384, 128);
  k_cvt<<<(N * 64 / 4 + 255) / 256, 256, 0, stream>>>(feats, featsb, N * 64 / 4);

  // --- (dstTile, relation) bucketing, once per launch ---
  k_zero<<<64, 256, 0, stream>>>(binCnt, NBIN);
  k_hist_bin<<<(E + 255) / 256, 256, 0, stream>>>(etype, dst, E, binCnt);
  k_scan_bin<<<1, 256, 0, stream>>>(binCnt, NBIN, binStart, binCur);
  k_place_bin<<<(E + 255) / 256, 256, 0, stream>>>(etype, src, dst, binCur, epk, E);

  const dim3 blk(256);
  const int gm = (N + 127) / 128;
  const dim3 g1(gm, 1), g2(gm, 2);

  // input projection
  gemm_bf16<<<g1, blk, 0, stream>>>(featsb, nullptr, 0, 64, 64, wt_in, b_in,
                                    xb0, nullptr, N, HID, 1);

  for (int l = 0; l < NL; l++) {
    const __bf16* xin = (l & 1) ? xb1 : xb0;
    __bf16* xout = (l & 1) ? xb0 : xb1;

    // fused: msg = b_rel + W_loop x + sum_r W_r (gather-sum x[src]), bf16 out
    node_msg<<<NT, blk, 0, stream>>>(xin,
                                     wt_rel + (size_t)l * NREL * HID * HID,
                                     wt_loop + (size_t)l * HID * HID,
                                     b_rel + (size_t)l * HID,
                                     binStart, epk, msgb, N);

    // mid = tanh([x | msg] @ W_u1[l] + b_u1[l])  (msg already bf16)
    gemm_bf16<<<g2, blk, 0, stream>>>(xin, msgb, 0, HID, 256,
                                      wt_u1 + (size_t)l * 256 * 256,
                                      b_u1 + (size_t)l * 256,
                                      mid, nullptr, N, 256, 1);

    // x' = tanh([x | mid] @ W_u2[l] + b_u2[l]); last layer -> f32 d_out
    gemm_bf16<<<g1, blk, 0, stream>>>(xin, mid, 0, HID, 384,
                                      wt_u2 + (size_t)l * HID * 384,
                                      b_u2 + (size_t)l * HID,
                                      (l == NL - 1) ? nullptr : xout,
                                      (l == NL - 1) ? (float*)d_out : nullptr,
                                      N, HID, 1);
  }
}

// Round 7
// 7519.698 us; speedup vs baseline: 1.0432x; 1.0046x over previous
//
#include <hip/hip_runtime.h>
#include <cstddef>

// ---------------------------------------------------------------------------
// RelGraphConv GNN, 10 layers. Round 7: node_msg gather restructured to the
// round-4-proven staging pattern: per relation, 2048 independent
// (row, 16B-chunk) tasks; ds_add_f32 is fire-and-forget so the 8 chunk loads
// per thread issue back-to-back (round 6 interleaved dependent loads with
// atomics -> fully serialized, 9.5k cyc per 4 edges).
// N=100000, E=600000, F=64, H=128, R=8.
// ---------------------------------------------------------------------------

#define HID 128
#define NREL 8
#define NL 10

typedef __attribute__((ext_vector_type(8))) __bf16 bf16x8;
typedef __attribute__((ext_vector_type(4))) float f32x4;

// --- batched transpose + f32->bf16: W[z][K][Nc] -> Wt[z][Nc][K] ---
__global__ __launch_bounds__(256) void k_transpose(const float* __restrict__ W,
                                                   __bf16* __restrict__ Wt,
                                                   int K, int Nc) {
  __shared__ float t[32][33];
  const float* Wz = W + (size_t)blockIdx.z * K * Nc;
  __bf16* Wtz = Wt + (size_t)blockIdx.z * K * Nc;
  int n0 = blockIdx.x * 32, k0 = blockIdx.y * 32;
#pragma unroll
  for (int i = 0; i < 4; i++) {
    int k = k0 + threadIdx.y + i * 8;
    int n = n0 + threadIdx.x;
    t[threadIdx.y + i * 8][threadIdx.x] = Wz[(size_t)k * Nc + n];
  }
  __syncthreads();
#pragma unroll
  for (int i = 0; i < 4; i++) {
    int n = n0 + threadIdx.y + i * 8;
    int k = k0 + threadIdx.x;
    Wtz[(size_t)n * K + k] = (__bf16)t[threadIdx.x][threadIdx.y + i * 8];
  }
}

// --- f32 -> bf16 elementwise (n4 = count/4) ---
__global__ __launch_bounds__(256) void k_cvt(const float* __restrict__ x,
                                             __bf16* __restrict__ y, int n4) {
  int i = blockIdx.x * 256 + threadIdx.x;
  if (i < n4) {
    float4 f = ((const float4*)x)[i];
    __bf16 o[4] = {(__bf16)f.x, (__bf16)f.y, (__bf16)f.z, (__bf16)f.w};
    *(uint2*)(y + (size_t)i * 4) = *(uint2*)o;
  }
}

// ====================== (dstTile, relation) bucketing =======================
__global__ __launch_bounds__(256) void k_zero(int* __restrict__ p, int n) {
  for (int i = blockIdx.x * 256 + threadIdx.x; i < n; i += gridDim.x * 256) p[i] = 0;
}

__global__ __launch_bounds__(256) void k_hist_bin(const int* __restrict__ et,
                                                  const int* __restrict__ dst,
                                                  int E, int* __restrict__ binCnt) {
  int e = blockIdx.x * 256 + threadIdx.x;
  if (e < E) atomicAdd(&binCnt[(dst[e] >> 7) * NREL + et[e]], 1);
}

__global__ __launch_bounds__(256) void k_scan_bin(const int* __restrict__ binCnt,
                                                  int nb, int* __restrict__ binStart,
                                                  int* __restrict__ binCur) {
  __shared__ int part[257];
  int chunk = (nb + 255) / 256;
  int lo = threadIdx.x * chunk, hi = min(nb, lo + chunk);
  int s = 0;
  for (int i = lo; i < hi; i++) s += binCnt[i];
  part[threadIdx.x] = s;
  __syncthreads();
  if (threadIdx.x == 0) {
    int a = 0;
    for (int i = 0; i < 256; i++) { int v = part[i]; part[i] = a; a += v; }
    part[256] = a;
    binStart[nb] = a;
  }
  __syncthreads();
  int run = part[threadIdx.x];
  for (int i = lo; i < hi; i++) {
    binStart[i] = run;
    binCur[i] = run;
    run += binCnt[i];
  }
}

// pack edge: src (17b) | local-dst (7b) << 17
__global__ __launch_bounds__(256) void k_place_bin(const int* __restrict__ et,
                                                   const int* __restrict__ src,
                                                   const int* __restrict__ dst,
                                                   int* __restrict__ binCur,
                                                   int* __restrict__ epk, int E) {
  int e = blockIdx.x * 256 + threadIdx.x;
  if (e < E) {
    int d = dst[e];
    int bin = (d >> 7) * NREL + et[e];
    int p = atomicAdd(&binCur[bin], 1);
    epk[p] = src[e] | ((d & 127) << 17);
  }
}

// ========================= fused dst-tile msg kernel ========================
// One block per 128-dst tile. acc = b + W_loop x + sum_r W_r S_r.
// Gather: per relation, (row, chunk) tasks with independent loads and
// fire-and-forget ds_add_f32 — no dependent-chain serialization.
__global__ __launch_bounds__(256) void node_msg(
    const __bf16* __restrict__ x,
    const __bf16* __restrict__ wt_rel_l,   // [8][128][128] (n-major)
    const __bf16* __restrict__ wt_loop_l,  // [128][128]
    const float* __restrict__ b_rel_l,     // [128]
    const int* __restrict__ binStart,
    const int* __restrict__ epk,
    __bf16* __restrict__ msgb, int N) {
  __shared__ float S[128][132];  // gather-sum tile, f32

  const int tid = threadIdx.x;
  const int g = blockIdx.x;
  const int d0 = g * 128;
  const int lane = tid & 63, w = tid >> 6;
  const int ml = lane & 15, q = lane >> 4;
  const int wr = (w >> 1) * 64, wc = (w & 1) * 64;

  f32x4 acc[4][4];
#pragma unroll
  for (int i = 0; i < 4; i++)
#pragma unroll
    for (int j = 0; j < 4; j++)
#pragma unroll
      for (int z = 0; z < 4; z++) acc[i][j][z] = 0.f;

  // ---- self-loop: A direct from global x, B direct from wt_loop ----
#pragma unroll
  for (int kk = 0; kk < 4; kk++) {
    bf16x8 af[4], bfr[4];
#pragma unroll
    for (int i = 0; i < 4; i++) {
      int rr = min(d0 + wr + i * 16 + ml, N - 1);  // clamp; tail discarded at write
      af[i] = *(const bf16x8*)(x + (size_t)rr * HID + kk * 32 + q * 8);
    }
#pragma unroll
    for (int j = 0; j < 4; j++)
      bfr[j] = *(const bf16x8*)(wt_loop_l + (size_t)(wc + j * 16 + ml) * HID +
                                kk * 32 + q * 8);
#pragma unroll
    for (int i = 0; i < 4; i++)
#pragma unroll
      for (int j = 0; j < 4; j++)
        acc[i][j] = __builtin_amdgcn_mfma_f32_16x16x32_bf16(af[i], bfr[j],
                                                            acc[i][j], 0, 0, 0);
  }

  // ---- relations ----
  for (int r = 0; r < NREL; r++) {
    __syncthreads();  // previous MFMA reads of S done
    for (int i = tid; i < 128 * 132 / 4; i += 256) ((f32x4*)S)[i] = (f32x4)0.f;
    __syncthreads();  // S zeroed

    // gather-sum: tasks = (row, 16B-chunk); 2048 tasks / 256 threads = 8 each.
    // All 8 loads independent; ds_add has no return -> no wave stall chain.
    int bidx = g * NREL + r;
    int lo = binStart[bidx];
    int cnt = binStart[bidx + 1] - lo;
    for (int base = 0; base < cnt; base += 128) {
      int nrow = min(128, cnt - base);
#pragma unroll
      for (int i = 0; i < 8; i++) {
        int task = tid + i * 256;
        int row = task >> 4;        // 0..127
        int kc = task & 15;         // 16B chunk (8 bf16)
        if (row < nrow) {
          int p = epk[lo + base + row];
          int s = p & 0x1FFFF, ld = p >> 17;
          bf16x8 v = *(const bf16x8*)(x + (size_t)s * HID + kc * 8);
#pragma unroll
          for (int z = 0; z < 8; z++)
            atomicAdd(&S[ld][kc * 8 + z], (float)v[z]);
        }
      }
    }
    __syncthreads();  // gather complete

    // MFMA: A from S (f32 -> bf16), B direct from global (L2-hot)
    const __bf16* W = wt_rel_l + (size_t)r * HID * HID;
#pragma unroll
    for (int kk = 0; kk < 4; kk++) {
      bf16x8 af[4], bfr[4];
#pragma unroll
      for (int i = 0; i < 4; i++) {
        const float* sp = &S[wr + i * 16 + ml][kk * 32 + q * 8];
        f32x4 a0 = *(const f32x4*)sp;
        f32x4 a1 = *(const f32x4*)(sp + 4);
        bf16x8 t;
        t[0] = (__bf16)a0[0]; t[1] = (__bf16)a0[1];
        t[2] = (__bf16)a0[2]; t[3] = (__bf16)a0[3];
        t[4] = (__bf16)a1[0]; t[5] = (__bf16)a1[1];
        t[6] = (__bf16)a1[2]; t[7] = (__bf16)a1[3];
        af[i] = t;
      }
#pragma unroll
      for (int j = 0; j < 4; j++)
        bfr[j] = *(const bf16x8*)(W + (size_t)(wc + j * 16 + ml) * HID +
                                  kk * 32 + q * 8);
#pragma unroll
      for (int i = 0; i < 4; i++)
#pragma unroll
        for (int j = 0; j < 4; j++)
          acc[i][j] = __builtin_amdgcn_mfma_f32_16x16x32_bf16(af[i], bfr[j],
                                                              acc[i][j], 0, 0, 0);
    }
  }

  // ---- epilogue: + bias, single non-atomic bf16 write ----
#pragma unroll
  for (int i = 0; i < 4; i++) {
#pragma unroll
    for (int z = 0; z < 4; z++) {
      int grow = d0 + wr + i * 16 + q * 4 + z;
      if (grow >= N) continue;
#pragma unroll
      for (int j = 0; j < 4; j++) {
        int col = wc + j * 16 + ml;
        msgb[(size_t)grow * HID + col] = (__bf16)(acc[i][j][z] + b_rel_l[col]);
      }
    }
  }
}

// ---------------------------------------------------------------------------
// bf16 MFMA GEMM (dense): C = act(concat(A0,A1) @ B + bias)   [proven]
// ---------------------------------------------------------------------------
__global__ __launch_bounds__(256) void gemm_bf16(
    const __bf16* __restrict__ A0, const void* __restrict__ A1v, int a1_f32,
    int K0, int K,
    const __bf16* __restrict__ Bt, const float* __restrict__ bias,
    __bf16* __restrict__ Cb, float* __restrict__ Cf,
    int M, int Nc, int act) {
  __shared__ __bf16 As[128][72];
  __shared__ __bf16 Bs[128][72];
  const int tid = threadIdx.x;
  const int m0 = blockIdx.x * 128;
  const int bn0 = blockIdx.y * 128;
  const int lane = tid & 63;
  const int w = tid >> 6;
  const int ml = lane & 15, q = lane >> 4;
  const int wr = (w >> 1) * 64, wc = (w & 1) * 64;
  const int KA1 = K - K0;

  f32x4 acc[4][4];
#pragma unroll
  for (int i = 0; i < 4; i++)
#pragma unroll
    for (int j = 0; j < 4; j++)
#pragma unroll
      for (int r = 0; r < 4; r++) acc[i][j][r] = 0.f;

  for (int k0 = 0; k0 < K; k0 += 64) {
#pragma unroll
    for (int i = 0; i < 4; i++) {
      int ci = tid + i * 256;
      int row = ci >> 3;
      int kc = ci & 7;
      int gk = k0 + kc * 8;
      int gr = m0 + row;
      bf16x8 va;
#pragma unroll
      for (int z = 0; z < 8; z++) va[z] = (__bf16)0.f;
      if (gr < M) {
        if (gk < K0) {
          va = *(const bf16x8*)(A0 + (size_t)gr * K0 + gk);
        } else if (!a1_f32) {
          va = *(const bf16x8*)((const __bf16*)A1v + (size_t)gr * KA1 + (gk - K0));
        } else {
          const float* p = (const float*)A1v + (size_t)gr * KA1 + (gk - K0);
          float4 f0 = *(const float4*)p;
          float4 f1 = *(const float4*)(p + 4);
          va[0] = (__bf16)f0.x; va[1] = (__bf16)f0.y;
          va[2] = (__bf16)f0.z; va[3] = (__bf16)f0.w;
          va[4] = (__bf16)f1.x; va[5] = (__bf16)f1.y;
          va[6] = (__bf16)f1.z; va[7] = (__bf16)f1.w;
        }
      }
      *(bf16x8*)(&As[row][kc * 8]) = va;
      bf16x8 vb = *(const bf16x8*)(Bt + (size_t)(bn0 + row) * K + gk);
      *(bf16x8*)(&Bs[row][kc * 8]) = vb;
    }
    __syncthreads();
#pragma unroll
    for (int kk = 0; kk < 2; kk++) {
      bf16x8 af[4], bfr[4];
#pragma unroll
      for (int i = 0; i < 4; i++)
        af[i] = *(const bf16x8*)(&As[wr + i * 16 + ml][kk * 32 + q * 8]);
#pragma unroll
      for (int j = 0; j < 4; j++)
        bfr[j] = *(const bf16x8*)(&Bs[wc + j * 16 + ml][kk * 32 + q * 8]);
#pragma unroll
      for (int i = 0; i < 4; i++)
#pragma unroll
        for (int j = 0; j < 4; j++)
          acc[i][j] = __builtin_amdgcn_mfma_f32_16x16x32_bf16(af[i], bfr[j],
                                                              acc[i][j], 0, 0, 0);
    }
    __syncthreads();
  }

#pragma unroll
  for (int i = 0; i < 4; i++) {
#pragma unroll
    for (int r = 0; r < 4; r++) {
      int grow = m0 + wr + i * 16 + q * 4 + r;
      if (grow >= M) continue;
#pragma unroll
      for (int j = 0; j < 4; j++) {
        int col = bn0 + wc + j * 16 + ml;
        float v = acc[i][j][r];
        if (bias) v += bias[col];
        if (act) v = tanhf(v);
        if (Cb) Cb[(size_t)grow * Nc + col] = (__bf16)v;
        if (Cf) Cf[(size_t)grow * Nc + col] = v;
      }
    }
  }
}

extern "C" void kernel_launch(void* const* d_in, const int* in_sizes, int n_in,
                              void* d_out, int out_size, void* d_ws, size_t ws_size,
                              hipStream_t stream) {
  const float* feats  = (const float*)d_in[0];
  const int*   src    = (const int*)d_in[1];
  const int*   dst    = (const int*)d_in[2];
  const int*   etype  = (const int*)d_in[3];
  const float* W_in   = (const float*)d_in[4];
  const float* b_in   = (const float*)d_in[5];
  const float* W_rel  = (const float*)d_in[6];
  const float* W_loop = (const float*)d_in[7];
  const float* b_rel  = (const float*)d_in[8];
  const float* W_u1   = (const float*)d_in[9];
  const float* b_u1   = (const float*)d_in[10];
  const float* W_u2   = (const float*)d_in[11];
  const float* b_u2   = (const float*)d_in[12];

  const int E = in_sizes[1];
  const int N = in_sizes[0] / 64;
  const int NT = (N + 127) / 128;      // dst tiles
  const int NBIN = NT * NREL;          // (tile, relation) bins

  // --- workspace layout ---
  __bf16* xb0 = (__bf16*)d_ws;                        // N*128
  __bf16* xb1 = xb0 + (size_t)N * HID;                // N*128
  __bf16* msgb = xb1 + (size_t)N * HID;               // N*128 bf16
  __bf16* mid = msgb + (size_t)N * HID;               // N*256 bf16
  __bf16* featsb = mid + (size_t)N * 256;             // N*64
  __bf16* wt_in   = featsb + (size_t)N * 64;          // [128][64]
  __bf16* wt_rel  = wt_in + 128 * 64;                 // [80][128][128]
  __bf16* wt_loop = wt_rel + (size_t)80 * 128 * 128;  // [10][128][128]
  __bf16* wt_u1   = wt_loop + (size_t)10 * 128 * 128; // [10][256][256]
  __bf16* wt_u2   = wt_u1 + (size_t)10 * 256 * 256;   // [10][128][384]
  int* binCnt   = (int*)(wt_u2 + (size_t)10 * 128 * 384); // NBIN
  int* binStart = binCnt + NBIN;                      // NBIN+1
  int* binCur   = binStart + NBIN + 1;                // NBIN
  int* epk      = binCur + NBIN;                      // E

  // --- weight transpose+convert + feats convert ---
  k_transpose<<<dim3(4, 2, 1),   dim3(32, 8), 0, stream>>>(W_in,   wt_in,   64, 128);
  k_transpose<<<dim3(4, 4, 80),  dim3(32, 8), 0, stream>>>(W_rel,  wt_rel,  128, 128);
  k_transpose<<<dim3(4, 4, 10),  dim3(32, 8), 0, stream>>>(W_loop, wt_loop, 128, 128);
  k_transpose<<<dim3(8, 8, 10),  dim3(32, 8), 0, stream>>>(W_u1,   wt_u1,   256, 256);
  k_transpose<<<dim3(4, 12, 10), dim3(32, 8), 0, stream>>>(W_u2,   wt_u2,   384, 128);
  k_cvt<<<(N * 64 / 4 + 255) / 256, 256, 0, stream>>>(feats, featsb, N * 64 / 4);

  // --- (dstTile, relation) bucketing, once per launch ---
  k_zero<<<64, 256, 0, stream>>>(binCnt, NBIN);
  k_hist_bin<<<(E + 255) / 256, 256, 0, stream>>>(etype, dst, E, binCnt);
  k_scan_bin<<<1, 256, 0, stream>>>(binCnt, NBIN, binStart, binCur);
  k_place_bin<<<(E + 255) / 256, 256, 0, stream>>>(etype, src, dst, binCur, epk, E);

  const dim3 blk(256);
  const int gm = (N + 127) / 128;
  const dim3 g1(gm, 1), g2(gm, 2);

  // input projection
  gemm_bf16<<<g1, blk, 0, stream>>>(featsb, nullptr, 0, 64, 64, wt_in, b_in,
                                    xb0, nullptr, N, HID, 1);

  for (int l = 0; l < NL; l++) {
    const __bf16* xin = (l & 1) ? xb1 : xb0;
    __bf16* xout = (l & 1) ? xb0 : xb1;

    // fused: msg = b_rel + W_loop x + sum_r W_r (gather-sum x[src]), bf16 out
    node_msg<<<NT, blk, 0, stream>>>(xin,
                                     wt_rel + (size_t)l * NREL * HID * HID,
                                     wt_loop + (size_t)l * HID * HID,
                                     b_rel + (size_t)l * HID,
                                     binStart, epk, msgb, N);

    // mid = tanh([x | msg] @ W_u1[l] + b_u1[l])  (msg already bf16)
    gemm_bf16<<<g2, blk, 0, stream>>>(xin, msgb, 0, HID, 256,
                                      wt_u1 + (size_t)l * 256 * 256,
                                      b_u1 + (size_t)l * 256,
                                      mid, nullptr, N, 256, 1);

    // x' = tanh([x | mid] @ W_u2[l] + b_u2[l]); last layer -> f32 d_out
    gemm_bf16<<<g1, blk, 0, stream>>>(xin, mid, 0, HID, 384,
                                      wt_u2 + (size_t)l * HID * 384,
                                      b_u2 + (size_t)l * HID,
                                      (l == NL - 1) ? nullptr : xout,
                                      (l == NL - 1) ? (float*)d_out : nullptr,
                                      N, HID, 1);
  }
}

// Round 8
// 4226.210 us; speedup vs baseline: 1.8561x; 1.7793x over previous
//
#include <hip/hip_runtime.h>
#include <cstddef>

// ---------------------------------------------------------------------------
// RelGraphConv GNN, 10 layers. Round 8: Z-GEMM + CSR segment-sum.
//   msg = b + W_loop x + sum_r W_r (segsum_r x)  computed as:
//     pass0: Z = x @ [W_0..W_3 | W_loop] (N x 640, dense MFMA GEMM)
//            seg0: msg[d] = b + Z[d,512:640] + sum_{e->d, r<4} Z[src_e, r*128:+128]
//     pass1: Z = x @ [W_4..W_7] (N x 512)
//            seg1: msg[d] += sum_{e->d, r>=4} Z[src_e, (r-4)*128:+128]
//   segsum: dst-sorted CSR, one 16-lane group per dst row — no atomics, no
//   LDS, no barriers, full occupancy (round 5-7's node_msg was structurally
//   latency-bound at 2 blocks/CU: 579 us; three micro-fixes did nothing).
// Z buffer (128 MB) aliases mid (dead during Z/segsum); ws ~214 MB.
// N=100000, E=600000, F=64, H=128, R=8.
// ---------------------------------------------------------------------------

#define HID 128
#define NREL 8
#define NL 10

typedef __attribute__((ext_vector_type(8))) __bf16 bf16x8;
typedef __attribute__((ext_vector_type(4))) float f32x4;

// --- batched transpose + f32->bf16: tile z: W[zi][K][Nc] -> Wt[zo][Nc][K] ---
// zi = (z/inDiv)*inScale + z%inDiv + inOff ; zo likewise.
__global__ __launch_bounds__(256) void k_transpose(const float* __restrict__ W,
                                                   __bf16* __restrict__ Wt,
                                                   int K, int Nc,
                                                   int inDiv, int inScale, int inOff,
                                                   int outDiv, int outScale, int outOff) {
  __shared__ float t[32][33];
  int z = blockIdx.z;
  int zi = (z / inDiv) * inScale + (z % inDiv) + inOff;
  int zo = (z / outDiv) * outScale + (z % outDiv) + outOff;
  const float* Wz = W + (size_t)zi * K * Nc;
  __bf16* Wtz = Wt + (size_t)zo * K * Nc;
  int n0 = blockIdx.x * 32, k0 = blockIdx.y * 32;
#pragma unroll
  for (int i = 0; i < 4; i++) {
    int k = k0 + threadIdx.y + i * 8;
    int n = n0 + threadIdx.x;
    t[threadIdx.y + i * 8][threadIdx.x] = Wz[(size_t)k * Nc + n];
  }
  __syncthreads();
#pragma unroll
  for (int i = 0; i < 4; i++) {
    int n = n0 + threadIdx.y + i * 8;
    int k = k0 + threadIdx.x;
    Wtz[(size_t)n * K + k] = (__bf16)t[threadIdx.x][threadIdx.y + i * 8];
  }
}

// --- f32 -> bf16 elementwise (n4 = count/4) ---
__global__ __launch_bounds__(256) void k_cvt(const float* __restrict__ x,
                                             __bf16* __restrict__ y, int n4) {
  int i = blockIdx.x * 256 + threadIdx.x;
  if (i < n4) {
    float4 f = ((const float4*)x)[i];
    __bf16 o[4] = {(__bf16)f.x, (__bf16)f.y, (__bf16)f.z, (__bf16)f.w};
    *(uint2*)(y + (size_t)i * 4) = *(uint2*)o;
  }
}

// ===================== dst-CSR build (once per launch) ======================
__global__ __launch_bounds__(256) void k_zero(int* __restrict__ p, int n) {
  for (int i = blockIdx.x * 256 + threadIdx.x; i < n; i += gridDim.x * 256) p[i] = 0;
}

__global__ __launch_bounds__(256) void k_hist_row(const int* __restrict__ dst,
                                                  int E, int* __restrict__ rowCnt) {
  int e = blockIdx.x * 256 + threadIdx.x;
  if (e < E) atomicAdd(&rowCnt[dst[e]], 1);
}

// single-block prefix sum: rowStart[0..nb], rowCur[0..nb-1]
__global__ __launch_bounds__(256) void k_scan_row(const int* __restrict__ rowCnt,
                                                  int nb, int* __restrict__ rowStart,
                                                  int* __restrict__ rowCur) {
  __shared__ int part[257];
  int chunk = (nb + 255) / 256;
  int lo = threadIdx.x * chunk, hi = min(nb, lo + chunk);
  int s = 0;
  for (int i = lo; i < hi; i++) s += rowCnt[i];
  part[threadIdx.x] = s;
  __syncthreads();
  if (threadIdx.x == 0) {
    int a = 0;
    for (int i = 0; i < 256; i++) { int v = part[i]; part[i] = a; a += v; }
    rowStart[nb] = a;
  }
  __syncthreads();
  int run = part[threadIdx.x];
  for (int i = lo; i < hi; i++) {
    rowStart[i] = run;
    rowCur[i] = run;
    run += rowCnt[i];
  }
}

// pack: src (17 bits) | etype << 17
__global__ __launch_bounds__(256) void k_place_row(const int* __restrict__ et,
                                                   const int* __restrict__ src,
                                                   const int* __restrict__ dst,
                                                   int* __restrict__ rowCur,
                                                   int* __restrict__ epk, int E) {
  int e = blockIdx.x * 256 + threadIdx.x;
  if (e < E) {
    int p = atomicAdd(&rowCur[dst[e]], 1);
    epk[p] = src[e] | (et[e] << 17);
  }
}

// ========================= CSR segment-sum kernel ===========================
// 16 lanes per dst row (lane covers 8 of 128 features), 16 rows per block.
// No LDS, no atomics: each row owned by exactly one lane-group.
// selfCol >= 0 (pass 0): acc = b_rel + Z[d][selfCol..]; else acc = msgb[d].
__global__ __launch_bounds__(256) void seg_sum(
    const __bf16* __restrict__ Z, const int* __restrict__ rowStart,
    const int* __restrict__ epk, const float* __restrict__ b_rel_l,
    __bf16* __restrict__ msgb, int N, int relBase, int zW, int selfCol) {
  int t16 = threadIdx.x & 15;
  int d = blockIdx.x * 16 + (threadIdx.x >> 4);
  if (d >= N) return;

  float acc[8];
  if (selfCol >= 0) {
    bf16x8 sv = *(const bf16x8*)(Z + (size_t)d * zW + selfCol + t16 * 8);
#pragma unroll
    for (int z = 0; z < 8; z++) acc[z] = (float)sv[z] + b_rel_l[t16 * 8 + z];
  } else {
    bf16x8 mv = *(const bf16x8*)(msgb + (size_t)d * HID + t16 * 8);
#pragma unroll
    for (int z = 0; z < 8; z++) acc[z] = (float)mv[z];
  }

  int lo = rowStart[d], hi = rowStart[d + 1];
  for (int e = lo; e < hi; e++) {
    int p = epk[e];
    int rr = (p >> 17) - relBase;
    if ((unsigned)rr < 4u) {
      bf16x8 v = *(const bf16x8*)(Z + (size_t)(p & 0x1FFFF) * zW + rr * HID + t16 * 8);
#pragma unroll
      for (int z = 0; z < 8; z++) acc[z] += (float)v[z];
    }
  }

  bf16x8 o;
#pragma unroll
  for (int z = 0; z < 8; z++) o[z] = (__bf16)acc[z];
  *(bf16x8*)(msgb + (size_t)d * HID + t16 * 8) = o;
}

// ---------------------------------------------------------------------------
// bf16 MFMA GEMM (dense): C = act(concat(A0,A1) @ B + bias)   [proven]
// ---------------------------------------------------------------------------
__global__ __launch_bounds__(256) void gemm_bf16(
    const __bf16* __restrict__ A0, const void* __restrict__ A1v, int a1_f32,
    int K0, int K,
    const __bf16* __restrict__ Bt, const float* __restrict__ bias,
    __bf16* __restrict__ Cb, float* __restrict__ Cf,
    int M, int Nc, int act) {
  __shared__ __bf16 As[128][72];
  __shared__ __bf16 Bs[128][72];
  const int tid = threadIdx.x;
  const int m0 = blockIdx.x * 128;
  const int bn0 = blockIdx.y * 128;
  const int lane = tid & 63;
  const int w = tid >> 6;
  const int ml = lane & 15, q = lane >> 4;
  const int wr = (w >> 1) * 64, wc = (w & 1) * 64;
  const int KA1 = K - K0;

  f32x4 acc[4][4];
#pragma unroll
  for (int i = 0; i < 4; i++)
#pragma unroll
    for (int j = 0; j < 4; j++)
#pragma unroll
      for (int r = 0; r < 4; r++) acc[i][j][r] = 0.f;

  for (int k0 = 0; k0 < K; k0 += 64) {
#pragma unroll
    for (int i = 0; i < 4; i++) {
      int ci = tid + i * 256;
      int row = ci >> 3;
      int kc = ci & 7;
      int gk = k0 + kc * 8;
      int gr = m0 + row;
      bf16x8 va;
#pragma unroll
      for (int z = 0; z < 8; z++) va[z] = (__bf16)0.f;
      if (gr < M) {
        if (gk < K0) {
          va = *(const bf16x8*)(A0 + (size_t)gr * K0 + gk);
        } else if (!a1_f32) {
          va = *(const bf16x8*)((const __bf16*)A1v + (size_t)gr * KA1 + (gk - K0));
        } else {
          const float* p = (const float*)A1v + (size_t)gr * KA1 + (gk - K0);
          float4 f0 = *(const float4*)p;
          float4 f1 = *(const float4*)(p + 4);
          va[0] = (__bf16)f0.x; va[1] = (__bf16)f0.y;
          va[2] = (__bf16)f0.z; va[3] = (__bf16)f0.w;
          va[4] = (__bf16)f1.x; va[5] = (__bf16)f1.y;
          va[6] = (__bf16)f1.z; va[7] = (__bf16)f1.w;
        }
      }
      *(bf16x8*)(&As[row][kc * 8]) = va;
      bf16x8 vb = *(const bf16x8*)(Bt + (size_t)(bn0 + row) * K + gk);
      *(bf16x8*)(&Bs[row][kc * 8]) = vb;
    }
    __syncthreads();
#pragma unroll
    for (int kk = 0; kk < 2; kk++) {
      bf16x8 af[4], bfr[4];
#pragma unroll
      for (int i = 0; i < 4; i++)
        af[i] = *(const bf16x8*)(&As[wr + i * 16 + ml][kk * 32 + q * 8]);
#pragma unroll
      for (int j = 0; j < 4; j++)
        bfr[j] = *(const bf16x8*)(&Bs[wc + j * 16 + ml][kk * 32 + q * 8]);
#pragma unroll
      for (int i = 0; i < 4; i++)
#pragma unroll
        for (int j = 0; j < 4; j++)
          acc[i][j] = __builtin_amdgcn_mfma_f32_16x16x32_bf16(af[i], bfr[j],
                                                              acc[i][j], 0, 0, 0);
    }
    __syncthreads();
  }

#pragma unroll
  for (int i = 0; i < 4; i++) {
#pragma unroll
    for (int r = 0; r < 4; r++) {
      int grow = m0 + wr + i * 16 + q * 4 + r;
      if (grow >= M) continue;
#pragma unroll
      for (int j = 0; j < 4; j++) {
        int col = bn0 + wc + j * 16 + ml;
        float v = acc[i][j][r];
        if (bias) v += bias[col];
        if (act) v = tanhf(v);
        if (Cb) Cb[(size_t)grow * Nc + col] = (__bf16)v;
        if (Cf) Cf[(size_t)grow * Nc + col] = v;
      }
    }
  }
}

extern "C" void kernel_launch(void* const* d_in, const int* in_sizes, int n_in,
                              void* d_out, int out_size, void* d_ws, size_t ws_size,
                              hipStream_t stream) {
  const float* feats  = (const float*)d_in[0];
  const int*   src    = (const int*)d_in[1];
  const int*   dst    = (const int*)d_in[2];
  const int*   etype  = (const int*)d_in[3];
  const float* W_in   = (const float*)d_in[4];
  const float* b_in   = (const float*)d_in[5];
  const float* W_rel  = (const float*)d_in[6];
  const float* W_loop = (const float*)d_in[7];
  const float* b_rel  = (const float*)d_in[8];
  const float* W_u1   = (const float*)d_in[9];
  const float* b_u1   = (const float*)d_in[10];
  const float* W_u2   = (const float*)d_in[11];
  const float* b_u2   = (const float*)d_in[12];

  const int E = in_sizes[1];
  const int N = in_sizes[0] / 64;
  const int TS = HID * HID;  // 16384 elems per weight tile

  // --- workspace layout (~214 MB) ---
  __bf16* xb0  = (__bf16*)d_ws;                       // N*128
  __bf16* xb1  = xb0 + (size_t)N * HID;               // N*128
  __bf16* msgb = xb1 + (size_t)N * HID;               // N*128
  __bf16* U    = msgb + (size_t)N * HID;              // N*640 (Z | mid | featsb)
  __bf16* Z    = U;
  __bf16* mid  = U;
  __bf16* featsb = U;
  __bf16* wt_in = U + (size_t)N * 640;                // [128][64]
  __bf16* wt_z0 = wt_in + 128 * 64;                   // [10][5][128][128]
  __bf16* wt_z1 = wt_z0 + (size_t)10 * 5 * TS;        // [10][4][128][128]
  __bf16* wt_u1 = wt_z1 + (size_t)10 * 4 * TS;        // [10][256][256]
  __bf16* wt_u2 = wt_u1 + (size_t)10 * 256 * 256;     // [10][128][384]
  int* rowCnt   = (int*)(wt_u2 + (size_t)10 * 128 * 384); // N
  int* rowStart = rowCnt + N;                         // N+1
  int* rowCur   = rowStart + N + 1;                   // N
  int* epk      = rowCur + N;                         // E

  // --- weight transpose+convert ---
  // W_in -> wt_in
  k_transpose<<<dim3(4, 2, 1), dim3(32, 8), 0, stream>>>(W_in, wt_in, 64, 128,
                                                         1, 1, 0, 1, 1, 0);
  // W_rel r<4 -> wt_z0 tiles (l*5 + r)
  k_transpose<<<dim3(4, 4, 40), dim3(32, 8), 0, stream>>>(W_rel, wt_z0, 128, 128,
                                                          4, 8, 0, 4, 5, 0);
  // W_rel r>=4 -> wt_z1 tiles (l*4 + r-4)
  k_transpose<<<dim3(4, 4, 40), dim3(32, 8), 0, stream>>>(W_rel, wt_z1, 128, 128,
                                                          4, 8, 4, 4, 4, 0);
  // W_loop -> wt_z0 tile (l*5 + 4)
  k_transpose<<<dim3(4, 4, 10), dim3(32, 8), 0, stream>>>(W_loop, wt_z0, 128, 128,
                                                          1, 1, 0, 1, 5, 4);
  // W_u1, W_u2
  k_transpose<<<dim3(8, 8, 10), dim3(32, 8), 0, stream>>>(W_u1, wt_u1, 256, 256,
                                                          1, 1, 0, 1, 1, 0);
  k_transpose<<<dim3(4, 12, 10), dim3(32, 8), 0, stream>>>(W_u2, wt_u2, 384, 128,
                                                           1, 1, 0, 1, 1, 0);
  k_cvt<<<(N * 64 / 4 + 255) / 256, 256, 0, stream>>>(feats, featsb, N * 64 / 4);

  // --- dst-CSR build (once; graph is layer-invariant) ---
  k_zero<<<128, 256, 0, stream>>>(rowCnt, N);
  k_hist_row<<<(E + 255) / 256, 256, 0, stream>>>(dst, E, rowCnt);
  k_scan_row<<<1, 256, 0, stream>>>(rowCnt, N, rowStart, rowCur);
  k_place_row<<<(E + 255) / 256, 256, 0, stream>>>(etype, src, dst, rowCur, epk, E);

  const dim3 blk(256);
  const int gm = (N + 127) / 128;
  const dim3 gseg((N + 15) / 16);

  // input projection: x0 = tanh(featsb @ W_in + b_in)  (featsb inside U: ok,
  // this GEMM writes xb0 only)
  gemm_bf16<<<dim3(gm, 1), blk, 0, stream>>>(featsb, nullptr, 0, 64, 64, wt_in,
                                             b_in, xb0, nullptr, N, HID, 1);

  for (int l = 0; l < NL; l++) {
    const __bf16* xin = (l & 1) ? xb1 : xb0;
    __bf16* xout = (l & 1) ? xb0 : xb1;

    // pass 0: Z = xin @ [W_0..3 | W_loop]  (N x 640)
    gemm_bf16<<<dim3(gm, 5), blk, 0, stream>>>(xin, nullptr, 0, HID, HID,
                                               wt_z0 + (size_t)l * 5 * TS,
                                               nullptr, Z, nullptr, N, 640, 0);
    // seg0: msg = b + Z_self + sum(r<4) edges
    seg_sum<<<gseg, blk, 0, stream>>>(Z, rowStart, epk, b_rel + (size_t)l * HID,
                                      msgb, N, 0, 640, 512);
    // pass 1: Z = xin @ [W_4..7]  (N x 512)
    gemm_bf16<<<dim3(gm, 4), blk, 0, stream>>>(xin, nullptr, 0, HID, HID,
                                               wt_z1 + (size_t)l * 4 * TS,
                                               nullptr, Z, nullptr, N, 512, 0);
    // seg1: msg += sum(r>=4) edges
    seg_sum<<<gseg, blk, 0, stream>>>(Z, rowStart, epk, nullptr,
                                      msgb, N, 4, 512, -1);

    // mid = tanh([x | msg] @ W_u1[l] + b_u1[l])   (mid aliases Z; Z is dead)
    gemm_bf16<<<dim3(gm, 2), blk, 0, stream>>>(xin, msgb, 0, HID, 256,
                                               wt_u1 + (size_t)l * 256 * 256,
                                               b_u1 + (size_t)l * 256,
                                               mid, nullptr, N, 256, 1);

    // x' = tanh([x | mid] @ W_u2[l] + b_u2[l]); last layer -> f32 d_out
    gemm_bf16<<<dim3(gm, 1), blk, 0, stream>>>(xin, mid, 0, HID, 384,
                                               wt_u2 + (size_t)l * HID * 384,
                                               b_u2 + (size_t)l * HID,
                                               (l == NL - 1) ? nullptr : xout,
                                               (l == NL - 1) ? (float*)d_out : nullptr,
                                               N, HID, 1);
  }
}